// Round 8
// baseline (223.456 us; speedup 1.0000x reference)
//
#include <hip/hip_runtime.h>

// Problem constants (match reference)
#define B 32
#define S 32
#define N 128
#define U 64
#define E 2
#define NCLS 5

// R8: 6 dispatches (was 7). Same step structure as R7 (kernel-boundary sync;
// 6 all-to-all rounds = algorithmic min depth; R3/R4: in-kernel cross-XCD
// per-step barriers ~90us/step = dead end). k_final is folded into the LAST
// k_step via a NON-WAITING last-arrival reduction: every block of batch b
// release-fences + fetch_add(cnt[b]); the 16th arrival acquire-fences and
// reduces the 16 partials itself (80 loads / 5 stores, one thread). No
// polling, no spinning -> none of the R3/R4 pathology. cnt[] is zeroed by
// block 0 of the FIRST dispatch (kernel-boundary visibility; poison-value
// independent).
//
// Each block: 8 rows of one batch (4 waves x 2 rows); lane = feature column.
// 256 thr, 34 KB LDS, VGPR<=128 -> 2 blocks/CU (R7 win: stall overlap).

__device__ __forceinline__ float sigmoid_f(float x) {
    return __fdividef(1.f, 1.f + __expf(-x));
}
__device__ __forceinline__ float tanh_f(float x) {
    float t = __expf(-2.f * fabsf(x));
    float y = __fdividef(1.f - t, 1.f + t);
    return copysignf(y, x);
}

template <int FIRST, int LAST>
__global__ __launch_bounds__(256) void k_step(
    const float* __restrict__ x, const int* __restrict__ lens,
    const float* __restrict__ hin, float* __restrict__ hout,
    const float* __restrict__ A, const float* __restrict__ Wmsg,
    const float* __restrict__ bmsg, const float* __restrict__ Wg,
    const float* __restrict__ Ug, const float* __restrict__ bg,
    const float* __restrict__ fcw, const float* __restrict__ fcb,
    float* __restrict__ partial, unsigned* __restrict__ cnt,
    float* __restrict__ out, int l) {
    __shared__ float hs[N * U];  // 32 KB: h[b] staged (all rows)
    __shared__ float bc[8 * U];  // 2 KB: wave-local broadcast buffer (own 2 rows)
    int tid = threadIdx.x;
    int wave = tid >> 6, lane = tid & 63;
    int b = blockIdx.x >> 4;
    int j = blockIdx.x & 15;
    int n0 = j * 8 + wave * 2;  // global row base (2 rows per wave)
    int r0 = wave * 2;          // local row base in bc

    if (FIRST) {
        // zero the last-arrival counters for the LAST dispatch (5 kernel
        // boundaries later -> visibility guaranteed)
        if (blockIdx.x == 0 && tid < B)
            __hip_atomic_store(&cnt[tid], 0u, __ATOMIC_RELAXED, __HIP_MEMORY_SCOPE_AGENT);
    }

    // ---- stage h[b] (all N rows) into LDS: 2048 float4 over 256 threads
    {
        const float* src;
        if (FIRST) {
            int idx = lens[b] - 1;
            idx = idx < 0 ? 0 : (idx > S - 1 ? S - 1 : idx);
            src = x + (size_t)(b * S + idx) * N * U;
        } else {
            src = hin + (size_t)b * N * U;
        }
        const float4* s4 = (const float4*)src;
        float4* d4 = (float4*)hs;
#pragma unroll
        for (int i = 0; i < 8; i++) d4[tid + i * 256] = s4[tid + i * 256];
    }
    __syncthreads();

    float hv0 = hs[(n0 + 0) * U + lane];
    float hv1 = hs[(n0 + 1) * U + lane];

    // ---- aggregate h: s[row][e] = sum_m A[b,e,row,m] * hs[m][lane]
    float s00 = 0.f, s01 = 0.f, s10 = 0.f, s11 = 0.f;  // [row][e]
    {
        const float4* A00 = (const float4*)(A + (((size_t)b * E + 0) * N + n0 + 0) * N);
        const float4* A10 = (const float4*)(A + (((size_t)b * E + 0) * N + n0 + 1) * N);
        const float4* A01 = (const float4*)(A + (((size_t)b * E + 1) * N + n0 + 0) * N);
        const float4* A11 = (const float4*)(A + (((size_t)b * E + 1) * N + n0 + 1) * N);
        for (int m4 = 0; m4 < N / 4; ++m4) {
            float4 a00 = A00[m4], a10 = A10[m4], a01 = A01[m4], a11 = A11[m4];
            float q0 = hs[(m4 * 4 + 0) * U + lane];
            float q1 = hs[(m4 * 4 + 1) * U + lane];
            float q2 = hs[(m4 * 4 + 2) * U + lane];
            float q3 = hs[(m4 * 4 + 3) * U + lane];
            s00 = fmaf(a00.x, q0, s00); s00 = fmaf(a00.y, q1, s00);
            s00 = fmaf(a00.z, q2, s00); s00 = fmaf(a00.w, q3, s00);
            s10 = fmaf(a10.x, q0, s10); s10 = fmaf(a10.y, q1, s10);
            s10 = fmaf(a10.z, q2, s10); s10 = fmaf(a10.w, q3, s10);
            s01 = fmaf(a01.x, q0, s01); s01 = fmaf(a01.y, q1, s01);
            s01 = fmaf(a01.z, q2, s01); s01 = fmaf(a01.w, q3, s01);
            s11 = fmaf(a11.x, q0, s11); s11 = fmaf(a11.y, q1, s11);
            s11 = fmaf(a11.z, q2, s11); s11 = fmaf(a11.w, q3, s11);
        }
    }

    // ---- a[row] = sum_e s[row][e] @ Wmsg[l][e] + bmsg[l]  (bc broadcast)
    float bm = bmsg[l * U + lane];
    float av0 = bm, av1 = bm;
    {
        const float* W0 = Wmsg + (size_t)(l * E + 0) * U * U;
        const float* W1 = Wmsg + (size_t)(l * E + 1) * U * U;
        bc[(r0 + 0) * U + lane] = s00;
        bc[(r0 + 1) * U + lane] = s10;
        for (int u4 = 0; u4 < U; u4 += 4) {
            float sa[4], sb[4];
            *(float4*)sa = *(const float4*)(bc + (r0 + 0) * U + u4);
            *(float4*)sb = *(const float4*)(bc + (r0 + 1) * U + u4);
#pragma unroll
            for (int k = 0; k < 4; ++k) {
                float w = W0[(u4 + k) * U + lane];
                av0 = fmaf(sa[k], w, av0);
                av1 = fmaf(sb[k], w, av1);
            }
        }
        bc[(r0 + 0) * U + lane] = s01;  // wave-local WAR on bc: in-order DS pipe
        bc[(r0 + 1) * U + lane] = s11;
        for (int u4 = 0; u4 < U; u4 += 4) {
            float sa[4], sb[4];
            *(float4*)sa = *(const float4*)(bc + (r0 + 0) * U + u4);
            *(float4*)sb = *(const float4*)(bc + (r0 + 1) * U + u4);
#pragma unroll
            for (int k = 0; k < 4; ++k) {
                float w = W1[(u4 + k) * U + lane];
                av0 = fmaf(sa[k], w, av0);
                av1 = fmaf(sb[k], w, av1);
            }
        }
    }

    // ---- gate matmuls (lane = output column v); a,h broadcasts via bc/hs b128
    const float* Wg0 = Wg + (size_t)l * 3 * U * U;
    const float* Wg1 = Wg0 + U * U;
    const float* Wg2 = Wg1 + U * U;
    const float* Ug0 = Ug + (size_t)l * 3 * U * U;
    const float* Ug1 = Ug0 + U * U;
    const float* Ug2 = Ug1 + U * U;
    float accz0 = bg[(l * 3 + 0) * U + lane], accz1 = accz0;
    float accr0 = bg[(l * 3 + 1) * U + lane], accr1 = accr0;
    float accc0 = bg[(l * 3 + 2) * U + lane], accc1 = accc0;
    bc[(r0 + 0) * U + lane] = av0;
    bc[(r0 + 1) * U + lane] = av1;
    for (int u4 = 0; u4 < U; u4 += 4) {
        float a0[4], a1[4], h0[4], h1[4];
        *(float4*)a0 = *(const float4*)(bc + (r0 + 0) * U + u4);
        *(float4*)a1 = *(const float4*)(bc + (r0 + 1) * U + u4);
        *(float4*)h0 = *(const float4*)(hs + (n0 + 0) * U + u4);
        *(float4*)h1 = *(const float4*)(hs + (n0 + 1) * U + u4);
#pragma unroll
        for (int k = 0; k < 4; ++k) {
            int u = u4 + k;
            float w0 = Wg0[u * U + lane], w1 = Wg1[u * U + lane], w2 = Wg2[u * U + lane];
            float g0 = Ug0[u * U + lane], g1 = Ug1[u * U + lane];
            accz0 = fmaf(a0[k], w0, accz0); accz0 = fmaf(h0[k], g0, accz0);
            accz1 = fmaf(a1[k], w0, accz1); accz1 = fmaf(h1[k], g0, accz1);
            accr0 = fmaf(a0[k], w1, accr0); accr0 = fmaf(h0[k], g1, accr0);
            accr1 = fmaf(a1[k], w1, accr1); accr1 = fmaf(h1[k], g1, accr1);
            accc0 = fmaf(a0[k], w2, accc0);
            accc1 = fmaf(a1[k], w2, accc1);
        }
    }
    float rg0 = sigmoid_f(accr0), rg1 = sigmoid_f(accr1);
    float rh0 = rg0 * hv0, rh1 = rg1 * hv1;
    bc[(r0 + 0) * U + lane] = rh0;  // overwrite av (fully consumed; wave-local)
    bc[(r0 + 1) * U + lane] = rh1;
    for (int u4 = 0; u4 < U; u4 += 4) {
        float p0[4], p1[4];
        *(float4*)p0 = *(const float4*)(bc + (r0 + 0) * U + u4);
        *(float4*)p1 = *(const float4*)(bc + (r0 + 1) * U + u4);
#pragma unroll
        for (int k = 0; k < 4; ++k) {
            float g2 = Ug2[(u4 + k) * U + lane];
            accc0 = fmaf(p0[k], g2, accc0);
            accc1 = fmaf(p1[k], g2, accc1);
        }
    }
    float zg0 = sigmoid_f(accz0), zg1 = sigmoid_f(accz1);
    float hn0 = (1.f - zg0) * hv0 + zg0 * tanh_f(accc0);
    float hn1 = (1.f - zg1) * hv1 + zg1 * tanh_f(accc1);

    if (!LAST) {
        hout[((size_t)b * N + n0 + 0) * U + lane] = hn0;
        hout[((size_t)b * N + n0 + 1) * U + lane] = hn1;
    } else {
        // fused classification partial: max over our 8 rows of relu(h')@fc_w
        float lg0[NCLS], lg1[NCLS];
        float rv0 = hn0 > 0.f ? hn0 : 0.f;
        float rv1 = hn1 > 0.f ? hn1 : 0.f;
#pragma unroll
        for (int c = 0; c < NCLS; c++) {
            float w = fcw[lane * NCLS + c];
            lg0[c] = rv0 * w;
            lg1[c] = rv1 * w;
        }
#pragma unroll
        for (int off = 32; off; off >>= 1) {
#pragma unroll
            for (int c = 0; c < NCLS; c++) {
                lg0[c] += __shfl_xor(lg0[c], off, 64);
                lg1[c] += __shfl_xor(lg1[c], off, 64);
            }
        }
        __syncthreads();  // all waves past bc/hs use; reuse bc as reduce buffer
        if (lane == 0) {
#pragma unroll
            for (int c = 0; c < NCLS; c++) bc[wave * NCLS + c] = fmaxf(lg0[c], lg1[c]);
        }
        __syncthreads();
        if (tid < NCLS) {
            float m = bc[tid];
            for (int w = 1; w < 4; ++w) m = fmaxf(m, bc[w * NCLS + tid]);
            partial[(size_t)(b * 16 + j) * NCLS + tid] = m;
        }
        __syncthreads();  // partial stores drained (compiler: waitcnt before barrier)

        // non-waiting last-arrival reduction: 16th block of batch b finishes it
        if (tid == 0) {
            __builtin_amdgcn_fence(__ATOMIC_RELEASE, "agent");
            unsigned old = __hip_atomic_fetch_add(&cnt[b], 1u, __ATOMIC_RELAXED,
                                                  __HIP_MEMORY_SCOPE_AGENT);
            if (old == 15u) {
                __builtin_amdgcn_fence(__ATOMIC_ACQUIRE, "agent");
#pragma unroll
                for (int c = 0; c < NCLS; ++c) {
                    float m = -3.4e38f;
                    for (int jj = 0; jj < 16; ++jj)
                        m = fmaxf(m, partial[(size_t)(b * 16 + jj) * NCLS + c]);
                    out[b * NCLS + c] = m + fcb[c];
                }
            }
        }
    }
}

// ---------------------------------------------------------------------------
extern "C" void kernel_launch(void* const* d_in, const int* in_sizes, int n_in,
                              void* d_out, int out_size, void* d_ws, size_t ws_size,
                              hipStream_t stream) {
    const float* x    = (const float*)d_in[0];
    const int*   lens = (const int*)d_in[1];
    const float* A    = (const float*)d_in[2];
    const float* Wmsg = (const float*)d_in[3];
    const float* bmsg = (const float*)d_in[4];
    const float* Wg   = (const float*)d_in[5];
    const float* Ug   = (const float*)d_in[6];
    const float* bg   = (const float*)d_in[7];
    const float* fcw  = (const float*)d_in[8];
    const float* fcb  = (const float*)d_in[9];
    float* out = (float*)d_out;

    float*    hA      = (float*)d_ws;                   // [B][N][U]
    float*    hB      = hA + (size_t)B * N * U;         // [B][N][U]
    float*    partial = hB + (size_t)B * N * U;         // [B][16][NCLS]
    unsigned* cnt     = (unsigned*)(partial + (size_t)B * 16 * NCLS);  // [B]

    // steps 0-2: layer 0; steps 3-5: layer 1; final reduce folded into LAST
    k_step<1, 0><<<B * 16, 256, 0, stream>>>(x, lens, nullptr, hA, A, Wmsg, bmsg, Wg, Ug, bg, fcw, fcb, partial, cnt, out, 0);
    k_step<0, 0><<<B * 16, 256, 0, stream>>>(x, lens, hA, hB, A, Wmsg, bmsg, Wg, Ug, bg, fcw, fcb, partial, cnt, out, 0);
    k_step<0, 0><<<B * 16, 256, 0, stream>>>(x, lens, hB, hA, A, Wmsg, bmsg, Wg, Ug, bg, fcw, fcb, partial, cnt, out, 0);
    k_step<0, 0><<<B * 16, 256, 0, stream>>>(x, lens, hA, hB, A, Wmsg, bmsg, Wg, Ug, bg, fcw, fcb, partial, cnt, out, 1);
    k_step<0, 0><<<B * 16, 256, 0, stream>>>(x, lens, hB, hA, A, Wmsg, bmsg, Wg, Ug, bg, fcw, fcb, partial, cnt, out, 1);
    k_step<0, 1><<<B * 16, 256, 0, stream>>>(x, lens, hA, hB, A, Wmsg, bmsg, Wg, Ug, bg, fcw, fcb, partial, cnt, out, 1);
}

// Round 9
// 214.456 us; speedup vs baseline: 1.0420x; 1.0420x over previous
//
#include <hip/hip_runtime.h>

// Problem constants (match reference)
#define B 32
#define S 32
#define N 128
#define U 64
#define E 2
#define NCLS 5

// R9 = revert to R7 (session best, 214.2us). R8's last-arrival reduction
// regressed (+9.3us): 512 agent-scope release fences at kernel tail cost more
// than the one dispatch they saved (generalizes R3/R4: on multi-XCD gfx950,
// fence cardinality -- not just spinning -- is the cost; kernel boundaries are
// the cheapest device-wide sync). Structure: 7 dispatches, kernel-boundary
// sync only; 6 all-to-all rounds = algorithmic min depth. Per-kernel: R6
// LDS-broadcast (wave-private bc rows, same-address ds_read_b128 replaces
// ds_bpermute __shfl), fast overflow-safe sigmoid/tanh, 256-thr blocks at
// 2 blocks/CU (R7: stall overlap across co-resident blocks).
//
// Each block: 8 rows of one batch (4 waves x 2 rows); lane = feature column.

__device__ __forceinline__ float sigmoid_f(float x) {
    return __fdividef(1.f, 1.f + __expf(-x));
}
__device__ __forceinline__ float tanh_f(float x) {
    float t = __expf(-2.f * fabsf(x));
    float y = __fdividef(1.f - t, 1.f + t);
    return copysignf(y, x);
}

template <int FIRST, int LAST>
__global__ __launch_bounds__(256) void k_step(
    const float* __restrict__ x, const int* __restrict__ lens,
    const float* __restrict__ hin, float* __restrict__ hout,
    const float* __restrict__ A, const float* __restrict__ Wmsg,
    const float* __restrict__ bmsg, const float* __restrict__ Wg,
    const float* __restrict__ Ug, const float* __restrict__ bg,
    const float* __restrict__ fcw, float* __restrict__ partial, int l) {
    __shared__ float hs[N * U];  // 32 KB: h[b] staged (all rows)
    __shared__ float bc[8 * U];  // 2 KB: wave-local broadcast buffer (own 2 rows)
    int tid = threadIdx.x;
    int wave = tid >> 6, lane = tid & 63;
    int b = blockIdx.x >> 4;
    int j = blockIdx.x & 15;
    int n0 = j * 8 + wave * 2;  // global row base (2 rows per wave)
    int r0 = wave * 2;          // local row base in bc

    // ---- stage h[b] (all N rows) into LDS: 2048 float4 over 256 threads
    {
        const float* src;
        if (FIRST) {
            int idx = lens[b] - 1;
            idx = idx < 0 ? 0 : (idx > S - 1 ? S - 1 : idx);
            src = x + (size_t)(b * S + idx) * N * U;
        } else {
            src = hin + (size_t)b * N * U;
        }
        const float4* s4 = (const float4*)src;
        float4* d4 = (float4*)hs;
#pragma unroll
        for (int i = 0; i < 8; i++) d4[tid + i * 256] = s4[tid + i * 256];
    }
    __syncthreads();

    float hv0 = hs[(n0 + 0) * U + lane];
    float hv1 = hs[(n0 + 1) * U + lane];

    // ---- aggregate h: s[row][e] = sum_m A[b,e,row,m] * hs[m][lane]
    float s00 = 0.f, s01 = 0.f, s10 = 0.f, s11 = 0.f;  // [row][e]
    {
        const float4* A00 = (const float4*)(A + (((size_t)b * E + 0) * N + n0 + 0) * N);
        const float4* A10 = (const float4*)(A + (((size_t)b * E + 0) * N + n0 + 1) * N);
        const float4* A01 = (const float4*)(A + (((size_t)b * E + 1) * N + n0 + 0) * N);
        const float4* A11 = (const float4*)(A + (((size_t)b * E + 1) * N + n0 + 1) * N);
        for (int m4 = 0; m4 < N / 4; ++m4) {
            float4 a00 = A00[m4], a10 = A10[m4], a01 = A01[m4], a11 = A11[m4];
            float q0 = hs[(m4 * 4 + 0) * U + lane];
            float q1 = hs[(m4 * 4 + 1) * U + lane];
            float q2 = hs[(m4 * 4 + 2) * U + lane];
            float q3 = hs[(m4 * 4 + 3) * U + lane];
            s00 = fmaf(a00.x, q0, s00); s00 = fmaf(a00.y, q1, s00);
            s00 = fmaf(a00.z, q2, s00); s00 = fmaf(a00.w, q3, s00);
            s10 = fmaf(a10.x, q0, s10); s10 = fmaf(a10.y, q1, s10);
            s10 = fmaf(a10.z, q2, s10); s10 = fmaf(a10.w, q3, s10);
            s01 = fmaf(a01.x, q0, s01); s01 = fmaf(a01.y, q1, s01);
            s01 = fmaf(a01.z, q2, s01); s01 = fmaf(a01.w, q3, s01);
            s11 = fmaf(a11.x, q0, s11); s11 = fmaf(a11.y, q1, s11);
            s11 = fmaf(a11.z, q2, s11); s11 = fmaf(a11.w, q3, s11);
        }
    }

    // ---- a[row] = sum_e s[row][e] @ Wmsg[l][e] + bmsg[l]  (bc broadcast)
    float bm = bmsg[l * U + lane];
    float av0 = bm, av1 = bm;
    {
        const float* W0 = Wmsg + (size_t)(l * E + 0) * U * U;
        const float* W1 = Wmsg + (size_t)(l * E + 1) * U * U;
        bc[(r0 + 0) * U + lane] = s00;
        bc[(r0 + 1) * U + lane] = s10;
        for (int u4 = 0; u4 < U; u4 += 4) {
            float sa[4], sb[4];
            *(float4*)sa = *(const float4*)(bc + (r0 + 0) * U + u4);
            *(float4*)sb = *(const float4*)(bc + (r0 + 1) * U + u4);
#pragma unroll
            for (int k = 0; k < 4; ++k) {
                float w = W0[(u4 + k) * U + lane];
                av0 = fmaf(sa[k], w, av0);
                av1 = fmaf(sb[k], w, av1);
            }
        }
        bc[(r0 + 0) * U + lane] = s01;  // wave-local WAR on bc: in-order DS pipe
        bc[(r0 + 1) * U + lane] = s11;
        for (int u4 = 0; u4 < U; u4 += 4) {
            float sa[4], sb[4];
            *(float4*)sa = *(const float4*)(bc + (r0 + 0) * U + u4);
            *(float4*)sb = *(const float4*)(bc + (r0 + 1) * U + u4);
#pragma unroll
            for (int k = 0; k < 4; ++k) {
                float w = W1[(u4 + k) * U + lane];
                av0 = fmaf(sa[k], w, av0);
                av1 = fmaf(sb[k], w, av1);
            }
        }
    }

    // ---- gate matmuls (lane = output column v); a,h broadcasts via bc/hs b128
    const float* Wg0 = Wg + (size_t)l * 3 * U * U;
    const float* Wg1 = Wg0 + U * U;
    const float* Wg2 = Wg1 + U * U;
    const float* Ug0 = Ug + (size_t)l * 3 * U * U;
    const float* Ug1 = Ug0 + U * U;
    const float* Ug2 = Ug1 + U * U;
    float accz0 = bg[(l * 3 + 0) * U + lane], accz1 = accz0;
    float accr0 = bg[(l * 3 + 1) * U + lane], accr1 = accr0;
    float accc0 = bg[(l * 3 + 2) * U + lane], accc1 = accc0;
    bc[(r0 + 0) * U + lane] = av0;
    bc[(r0 + 1) * U + lane] = av1;
    for (int u4 = 0; u4 < U; u4 += 4) {
        float a0[4], a1[4], h0[4], h1[4];
        *(float4*)a0 = *(const float4*)(bc + (r0 + 0) * U + u4);
        *(float4*)a1 = *(const float4*)(bc + (r0 + 1) * U + u4);
        *(float4*)h0 = *(const float4*)(hs + (n0 + 0) * U + u4);
        *(float4*)h1 = *(const float4*)(hs + (n0 + 1) * U + u4);
#pragma unroll
        for (int k = 0; k < 4; ++k) {
            int u = u4 + k;
            float w0 = Wg0[u * U + lane], w1 = Wg1[u * U + lane], w2 = Wg2[u * U + lane];
            float g0 = Ug0[u * U + lane], g1 = Ug1[u * U + lane];
            accz0 = fmaf(a0[k], w0, accz0); accz0 = fmaf(h0[k], g0, accz0);
            accz1 = fmaf(a1[k], w0, accz1); accz1 = fmaf(h1[k], g0, accz1);
            accr0 = fmaf(a0[k], w1, accr0); accr0 = fmaf(h0[k], g1, accr0);
            accr1 = fmaf(a1[k], w1, accr1); accr1 = fmaf(h1[k], g1, accr1);
            accc0 = fmaf(a0[k], w2, accc0);
            accc1 = fmaf(a1[k], w2, accc1);
        }
    }
    float rg0 = sigmoid_f(accr0), rg1 = sigmoid_f(accr1);
    float rh0 = rg0 * hv0, rh1 = rg1 * hv1;
    bc[(r0 + 0) * U + lane] = rh0;  // overwrite av (fully consumed; wave-local)
    bc[(r0 + 1) * U + lane] = rh1;
    for (int u4 = 0; u4 < U; u4 += 4) {
        float p0[4], p1[4];
        *(float4*)p0 = *(const float4*)(bc + (r0 + 0) * U + u4);
        *(float4*)p1 = *(const float4*)(bc + (r0 + 1) * U + u4);
#pragma unroll
        for (int k = 0; k < 4; ++k) {
            float g2 = Ug2[(u4 + k) * U + lane];
            accc0 = fmaf(p0[k], g2, accc0);
            accc1 = fmaf(p1[k], g2, accc1);
        }
    }
    float zg0 = sigmoid_f(accz0), zg1 = sigmoid_f(accz1);
    float hn0 = (1.f - zg0) * hv0 + zg0 * tanh_f(accc0);
    float hn1 = (1.f - zg1) * hv1 + zg1 * tanh_f(accc1);

    if (!LAST) {
        hout[((size_t)b * N + n0 + 0) * U + lane] = hn0;
        hout[((size_t)b * N + n0 + 1) * U + lane] = hn1;
    } else {
        // fused classification partial: max over our 8 rows of relu(h')@fc_w
        float lg0[NCLS], lg1[NCLS];
        float rv0 = hn0 > 0.f ? hn0 : 0.f;
        float rv1 = hn1 > 0.f ? hn1 : 0.f;
#pragma unroll
        for (int c = 0; c < NCLS; c++) {
            float w = fcw[lane * NCLS + c];
            lg0[c] = rv0 * w;
            lg1[c] = rv1 * w;
        }
#pragma unroll
        for (int off = 32; off; off >>= 1) {
#pragma unroll
            for (int c = 0; c < NCLS; c++) {
                lg0[c] += __shfl_xor(lg0[c], off, 64);
                lg1[c] += __shfl_xor(lg1[c], off, 64);
            }
        }
        __syncthreads();  // all waves past bc/hs use; reuse bc as reduce buffer
        if (lane == 0) {
#pragma unroll
            for (int c = 0; c < NCLS; c++) bc[wave * NCLS + c] = fmaxf(lg0[c], lg1[c]);
        }
        __syncthreads();
        if (tid < NCLS) {
            float m = bc[tid];
            for (int w = 1; w < 4; ++w) m = fmaxf(m, bc[w * NCLS + tid]);
            partial[(size_t)(b * 16 + j) * NCLS + tid] = m;
        }
    }
}

// ---------------------------------------------------------------------------
// k_final: out[b][c] = max over 16 block-partials + fc_b
__global__ void k_final(const float* __restrict__ partial, const float* __restrict__ fcb,
                        float* __restrict__ out) {
    int b = blockIdx.x, c = threadIdx.x;
    if (c < NCLS) {
        float m = -3.4e38f;
        for (int jj = 0; jj < 16; ++jj)
            m = fmaxf(m, partial[(size_t)(b * 16 + jj) * NCLS + c]);
        out[b * NCLS + c] = m + fcb[c];
    }
}

// ---------------------------------------------------------------------------
extern "C" void kernel_launch(void* const* d_in, const int* in_sizes, int n_in,
                              void* d_out, int out_size, void* d_ws, size_t ws_size,
                              hipStream_t stream) {
    const float* x    = (const float*)d_in[0];
    const int*   lens = (const int*)d_in[1];
    const float* A    = (const float*)d_in[2];
    const float* Wmsg = (const float*)d_in[3];
    const float* bmsg = (const float*)d_in[4];
    const float* Wg   = (const float*)d_in[5];
    const float* Ug   = (const float*)d_in[6];
    const float* bg   = (const float*)d_in[7];
    const float* fcw  = (const float*)d_in[8];
    const float* fcb  = (const float*)d_in[9];
    float* out = (float*)d_out;

    float* hA      = (float*)d_ws;                   // [B][N][U]
    float* hB      = hA + (size_t)B * N * U;         // [B][N][U]
    float* partial = hB + (size_t)B * N * U;         // [B][16][NCLS]

    // steps 0-2: layer 0; steps 3-5: layer 1
    k_step<1, 0><<<B * 16, 256, 0, stream>>>(x, lens, nullptr, hA, A, Wmsg, bmsg, Wg, Ug, bg, fcw, partial, 0);
    k_step<0, 0><<<B * 16, 256, 0, stream>>>(x, lens, hA, hB, A, Wmsg, bmsg, Wg, Ug, bg, fcw, partial, 0);
    k_step<0, 0><<<B * 16, 256, 0, stream>>>(x, lens, hB, hA, A, Wmsg, bmsg, Wg, Ug, bg, fcw, partial, 0);
    k_step<0, 0><<<B * 16, 256, 0, stream>>>(x, lens, hA, hB, A, Wmsg, bmsg, Wg, Ug, bg, fcw, partial, 1);
    k_step<0, 0><<<B * 16, 256, 0, stream>>>(x, lens, hB, hA, A, Wmsg, bmsg, Wg, Ug, bg, fcw, partial, 1);
    k_step<0, 1><<<B * 16, 256, 0, stream>>>(x, lens, hA, hB, A, Wmsg, bmsg, Wg, Ug, bg, fcw, partial, 1);
    k_final<<<B, 64, 0, stream>>>(partial, fcb, out);
}